// Round 4
// baseline (169.227 us; speedup 1.0000x reference)
//
#include <hip/hip_runtime.h>
#include <math.h>

#define H 8
#define B 8
#define C 512
#define L 1024
#define D 64
#define LDK 72   // bf16 LDS row stride: 144 B = 16B-aligned

typedef __attribute__((ext_vector_type(4))) float f32x4;
typedef __attribute__((ext_vector_type(8))) short bf16x8;

static __device__ __forceinline__ short f2bf(float x) {      // RNE
    union { float f; unsigned u; } v; v.f = x;
    unsigned r = v.u + 0x7FFFu + ((v.u >> 16) & 1u);
    return (short)(r >> 16);
}
static __device__ __forceinline__ short f2bf_fast(float x) { // round-half-up
    union { float f; unsigned u; } v; v.f = x;
    return (short)((v.u + 0x8000u) >> 16);
}
static __device__ __forceinline__ int pack2(short a, short b) {
    return (int)((unsigned short)a | ((unsigned)(unsigned short)b << 16));
}
static __device__ __forceinline__ float bf_lo(unsigned u) {
    union { unsigned u; float f; } v; v.u = u << 16; return v.f;
}
static __device__ __forceinline__ float bf_hi(unsigned u) {
    union { unsigned u; float f; } v; v.u = u & 0xFFFF0000u; return v.f;
}

// ---------------------------------------------------------------------------
// Weight prep -> bf16 A-fragment order [((conv*8+h)*3+t)*2+khalf][d][quad][jj].
// wq additionally scaled by (1/sqrt(H))*log2(e) so flash softmax runs in exp2.
// ---------------------------------------------------------------------------
__global__ __launch_bounds__(256) void wprep_kernel(
    const float* __restrict__ wq, const float* __restrict__ wk,
    const float* __restrict__ wv, short* __restrict__ wtg)
{
    int idx = blockIdx.x * 256 + threadIdx.x;       // < 294912
    int jj    = idx & 7;
    int quad  = (idx >> 3) & 3;
    int d     = (idx >> 5) & 63;
    int r     = idx >> 11;
    int khalf = r & 1;  r >>= 1;
    int t     = r % 3;  r /= 3;
    int h     = r & 7;
    int conv  = r >> 3;
    const float* w = (conv == 0) ? wq : (conv == 1) ? wk : wv;
    int j_in = khalf * 32 + quad * 8 + jj;
    float v = w[(h * 64 + d) * 192 + j_in * 3 + t];
    if (conv == 0) v *= 0.51012254f;                // (1/sqrt(8)) * log2(e)
    wtg[idx] = f2bf(v);
}

// ---------------------------------------------------------------------------
// Grouped conv1d as bf16 MFMA (unchanged structure from round 3).
// ---------------------------------------------------------------------------
__global__ __launch_bounds__(256) void conv_kernel(
    const float* __restrict__ q, const float* __restrict__ k,
    const short* __restrict__ wtg,
    short* __restrict__ qh, short* __restrict__ kh, short* __restrict__ vh)
{
    int bx   = blockIdx.x;
    int tile = bx & 15;
    int h    = (bx >> 4) & 7;
    int b    = (bx >> 7) & 7;
    int src  = bx >> 10;                 // 0: q->qh   1: k->kh+vh

    __shared__ short xT[66 * LDK];       // [p][j], p = l0-1 .. l0+64

    int l0  = tile * 64;
    int tid = threadIdx.x;
    int wave = tid >> 6, lane = tid & 63;
    int n = lane & 15, quad = lane >> 4;

    const float* x  = src ? k : q;
    const float* xb = x + (size_t)(b * C + h * 64) * L + l0;

    int c0 = src ? 1 : 0;
    const short* wb0 = wtg + (size_t)((c0 * 8 + h) * 3 * 2) * 2048;
    bf16x8 wf[3][2], wf2[3][2];
    #pragma unroll
    for (int t = 0; t < 3; t++)
        #pragma unroll
        for (int kk = 0; kk < 2; kk++)
            wf[t][kk] = *(const bf16x8*)(wb0 + (t * 2 + kk) * 2048
                                         + (wave * 16 + n) * 32 + quad * 8);
    if (src) {
        const short* wb1 = wtg + (size_t)((2 * 8 + h) * 3 * 2) * 2048;
        #pragma unroll
        for (int t = 0; t < 3; t++)
            #pragma unroll
            for (int kk = 0; kk < 2; kk++)
                wf2[t][kk] = *(const bf16x8*)(wb1 + (t * 2 + kk) * 2048
                                              + (wave * 16 + n) * 32 + quad * 8);
    }

    {
        int j = tid >> 2;
        #pragma unroll
        for (int s = 0; s < 4; s++) {
            int i = (tid & 3) + s * 4;
            float4 v = *(const float4*)(xb + j * L + i * 4);
            int p = 1 + i * 4;
            xT[(p + 0) * LDK + j] = f2bf(v.x);
            xT[(p + 1) * LDK + j] = f2bf(v.y);
            xT[(p + 2) * LDK + j] = f2bf(v.z);
            xT[(p + 3) * LDK + j] = f2bf(v.w);
        }
        if (tid < 64) {
            int gl = (l0 == 0) ? 1 : (l0 - 1);
            xT[0 * LDK + tid] = f2bf(x[(size_t)(b * C + h * 64 + tid) * L + gl]);
        } else if (tid < 128) {
            int j2 = tid - 64;
            int gl = (l0 + 64 >= L) ? (L - 2) : (l0 + 64);
            xT[65 * LDK + j2] = f2bf(x[(size_t)(b * C + h * 64 + j2) * L + gl]);
        }
    }
    __syncthreads();

    f32x4 acc[4], acc2[4];
    #pragma unroll
    for (int bl = 0; bl < 4; bl++) {
        acc[bl]  = (f32x4){0.f, 0.f, 0.f, 0.f};
        acc2[bl] = (f32x4){0.f, 0.f, 0.f, 0.f};
    }

    #pragma unroll
    for (int bl = 0; bl < 4; bl++) {
        #pragma unroll
        for (int t = 0; t < 3; t++) {
            #pragma unroll
            for (int kk = 0; kk < 2; kk++) {
                bf16x8 bf = *(const bf16x8*)&xT[(bl * 16 + n + t) * LDK
                                                + kk * 32 + quad * 8];
                acc[bl] = __builtin_amdgcn_mfma_f32_16x16x32_bf16(
                    wf[t][kk], bf, acc[bl], 0, 0, 0);
                if (src)
                    acc2[bl] = __builtin_amdgcn_mfma_f32_16x16x32_bf16(
                        wf2[t][kk], bf, acc2[bl], 0, 0, 0);
            }
        }
    }

    int bhh = b * H + h;
    short* o1 = src ? kh : qh;
    {
        short* ob = o1 + ((size_t)bhh * L + l0) * 64;
        #pragma unroll
        for (int bl = 0; bl < 4; bl++) {
            int lg = bl * 16 + n;
            int2 v;
            v.x = pack2(f2bf(acc[bl][0]), f2bf(acc[bl][1]));
            v.y = pack2(f2bf(acc[bl][2]), f2bf(acc[bl][3]));
            *(int2*)&ob[lg * 64 + wave * 16 + quad * 4] = v;
        }
    }
    if (src) {
        short* ob = vh + (size_t)bhh * 64 * L + l0;
        #pragma unroll
        for (int bl = 0; bl < 4; bl++)
            #pragma unroll
            for (int r = 0; r < 4; r++)
                ob[(wave * 16 + quad * 4 + r) * L + bl * 16 + n] = f2bf(acc2[bl][r]);
    }
}

// ---------------------------------------------------------------------------
// Causal flash attention, bf16 MFMA, 128 q-rows/WG, register-prefetched K/V.
// Wave w owns q-row blocks {w*16..}, {64+w*16..} (one per half -> balanced).
// qh pre-scaled so S is already in log2 domain (softmax via exp2).
// Ps aliases the Q buffer; P writes XOR-swizzled (col ^= quad*16) ->
// conflict-free b16 writes, aligned b128 A-frag reads.
// o written bf16 [B, L, C].
// ---------------------------------------------------------------------------
__global__ __launch_bounds__(256, 3) void flash_kernel(
    const short* __restrict__ qh, const short* __restrict__ kh,
    const short* __restrict__ vh, short* __restrict__ o)
{
    int bx  = blockIdx.x;
    int bh  = bx & 63;
    int qt2 = 7 - (bx >> 6);             // heavy q-tiles dispatch first
    int h   = bh & 7, b = bh >> 3;

    __shared__ short QPs[128 * LDK];     // Q tile, then P (per-wave rows)
    __shared__ short Ks[64 * LDK];       // [key][d]
    __shared__ short Vt[64 * LDK];       // [d][key]

    int tid = threadIdx.x, wave = tid >> 6, lane = tid & 63;
    int n = lane & 15, quad = lane >> 4;

    // stage Q (128 x 64 bf16)
    const short* Qg = qh + ((size_t)bh * L + qt2 * 128) * 64;
    #pragma unroll
    for (int jj = 0; jj < 4; jj++) {
        int i = tid + jj * 256;
        int row = i >> 3, ch = i & 7;
        *(int4*)&QPs[row * LDK + ch * 8] = ((const int4*)Qg)[i];
    }

    int ktmax = 2 * qt2 + 2;
    const short* Kbase = kh + (size_t)bh * L * 64;
    const short* Vbase = vh + (size_t)bh * 64 * L;
    int r0 = tid >> 3,         ch0 = tid & 7;
    int r1 = (tid + 256) >> 3, ch1 = (tid + 256) & 7;

    int4 kreg0, kreg1, vreg0, vreg1;
    kreg0 = ((const int4*)Kbase)[tid];
    kreg1 = ((const int4*)Kbase)[tid + 256];
    vreg0 = *(const int4*)(Vbase + r0 * L + ch0 * 8);
    vreg1 = *(const int4*)(Vbase + r1 * L + ch1 * 8);

    __syncthreads();
    bf16x8 qa[2][2];
    #pragma unroll
    for (int g = 0; g < 2; g++) {
        qa[g][0] = *(const bf16x8*)&QPs[(g * 64 + wave * 16 + n) * LDK + quad * 8];
        qa[g][1] = *(const bf16x8*)&QPs[(g * 64 + wave * 16 + n) * LDK + 32 + quad * 8];
    }

    f32x4 O[2][4];
    float mi[2][4], li[2][4];
    #pragma unroll
    for (int g = 0; g < 2; g++)
        #pragma unroll
        for (int r = 0; r < 4; r++) {
            O[g][r] = (f32x4){0.f, 0.f, 0.f, 0.f};
            mi[g][r] = -INFINITY; li[g][r] = 0.f;
        }

    int swz = ((n >> 2) & 3) << 4;       // read-side column swizzle

    for (int kt = 0; kt < ktmax; kt++) {
        __syncthreads();                 // all waves done with prev K/V
        *(int4*)&Ks[r0 * LDK + ch0 * 8] = kreg0;
        *(int4*)&Ks[r1 * LDK + ch1 * 8] = kreg1;
        *(int4*)&Vt[r0 * LDK + ch0 * 8] = vreg0;
        *(int4*)&Vt[r1 * LDK + ch1 * 8] = vreg1;
        __syncthreads();                 // stores visible
        if (kt + 1 < ktmax) {            // prefetch AFTER barrier, BEFORE compute
            const int4* Kg = (const int4*)(Kbase + (size_t)(kt + 1) * 64 * 64);
            kreg0 = Kg[tid]; kreg1 = Kg[tid + 256];
            const short* Vg = Vbase + (kt + 1) * 64;
            vreg0 = *(const int4*)(Vg + r0 * L + ch0 * 8);
            vreg1 = *(const int4*)(Vg + r1 * L + ch1 * 8);
        }

        bool lastTile = (kt == ktmax - 1);
        bool maskTile = (kt == ktmax - 2);

        #pragma unroll
        for (int g = 0; g < 2; g++) {
            if (g == 0 && lastTile) continue;   // fully masked half

            f32x4 s[4];
            #pragma unroll
            for (int bk = 0; bk < 4; bk++) {
                bf16x8 kb0 = *(const bf16x8*)&Ks[(bk * 16 + n) * LDK + quad * 8];
                bf16x8 kb1 = *(const bf16x8*)&Ks[(bk * 16 + n) * LDK + 32 + quad * 8];
                f32x4 acc = {0.f, 0.f, 0.f, 0.f};
                acc = __builtin_amdgcn_mfma_f32_16x16x32_bf16(qa[g][0], kb0, acc, 0, 0, 0);
                acc = __builtin_amdgcn_mfma_f32_16x16x32_bf16(qa[g][1], kb1, acc, 0, 0, 0);
                s[bk] = acc;
            }

            if ((g == 0 && maskTile) || (g == 1 && lastTile)) {
                int rowl = wave * 16 + quad * 4;
                #pragma unroll
                for (int bk = 0; bk < 4; bk++)
                    #pragma unroll
                    for (int r = 0; r < 4; r++)
                        if (bk * 16 + n > rowl + r) s[bk][r] = -INFINITY;
            }

            float rmax[4], rsum[4], alpha[4];
            #pragma unroll
            for (int r = 0; r < 4; r++)
                rmax[r] = fmaxf(fmaxf(s[0][r], s[1][r]), fmaxf(s[2][r], s[3][r]));
            #pragma unroll
            for (int off = 1; off < 16; off <<= 1)
                #pragma unroll
                for (int r = 0; r < 4; r++)
                    rmax[r] = fmaxf(rmax[r], __shfl_xor(rmax[r], off, 64));

            #pragma unroll
            for (int r = 0; r < 4; r++) {
                float mnew = fmaxf(mi[g][r], rmax[r]);
                alpha[r] = exp2f(mi[g][r] - mnew);
                mi[g][r] = mnew;
                float ls = 0.f;
                #pragma unroll
                for (int bk = 0; bk < 4; bk++) {
                    float p = exp2f(s[bk][r] - mnew);   // masked -> 0
                    s[bk][r] = p;
                    ls += p;
                }
                rsum[r] = ls;
            }
            #pragma unroll
            for (int off = 1; off < 16; off <<= 1)
                #pragma unroll
                for (int r = 0; r < 4; r++)
                    rsum[r] += __shfl_xor(rsum[r], off, 64);

            #pragma unroll
            for (int r = 0; r < 4; r++) {
                li[g][r] = li[g][r] * alpha[r] + rsum[r];
                #pragma unroll
                for (int bk = 0; bk < 4; bk++) O[g][bk][r] *= alpha[r];
            }

            // P -> LDS (swizzled), per-wave rows, no barrier
            #pragma unroll
            for (int bk = 0; bk < 4; bk++) {
                int col = ((bk ^ quad) << 4) + n;
                #pragma unroll
                for (int r = 0; r < 4; r++)
                    QPs[(g * 64 + wave * 16 + quad * 4 + r) * LDK + col] =
                        f2bf_fast(s[bk][r]);
            }

            bf16x8 pa0 = *(const bf16x8*)&QPs[(g * 64 + wave * 16 + n) * LDK
                                              + ((quad * 8) ^ swz)];
            bf16x8 pa1 = *(const bf16x8*)&QPs[(g * 64 + wave * 16 + n) * LDK
                                              + ((32 + quad * 8) ^ swz)];

            #pragma unroll
            for (int bk = 0; bk < 4; bk++) {
                bf16x8 v0 = *(const bf16x8*)&Vt[(bk * 16 + n) * LDK + quad * 8];
                bf16x8 v1 = *(const bf16x8*)&Vt[(bk * 16 + n) * LDK + 32 + quad * 8];
                O[g][bk] = __builtin_amdgcn_mfma_f32_16x16x32_bf16(pa0, v0, O[g][bk], 0, 0, 0);
                O[g][bk] = __builtin_amdgcn_mfma_f32_16x16x32_bf16(pa1, v1, O[g][bk], 0, 0, 0);
            }
        }
    }

    // epilogue: o[b][l][h*64 + col] bf16
    #pragma unroll
    for (int g = 0; g < 2; g++)
        #pragma unroll
        for (int r = 0; r < 4; r++) {
            float inv = 1.f / li[g][r];
            int lg = qt2 * 128 + g * 64 + wave * 16 + quad * 4 + r;
            short* ob = o + ((size_t)b * L + lg) * C + h * 64;
            ob[n]      = f2bf_fast(O[g][0][r] * inv);
            ob[16 + n] = f2bf_fast(O[g][1][r] * inv);
            ob[32 + n] = f2bf_fast(O[g][2][r] * inv);
            ob[48 + n] = f2bf_fast(O[g][3][r] * inv);
        }
}

// ---------------------------------------------------------------------------
// Residual + LayerNorm over channels; o is bf16 [B,L,C]; y fp32 [B,C,L].
// One WG = (b, 16-l tile). All global accesses vectorized.
// ---------------------------------------------------------------------------
__global__ __launch_bounds__(256) void ln_kernel(
    const short* __restrict__ o, const float* __restrict__ q,
    const float* __restrict__ gamma, const float* __restrict__ beta,
    float* __restrict__ y)
{
    int bx = blockIdx.x;
    int tile = bx & 63;
    int b = bx >> 6;
    int l0 = tile * 16;
    int tid = threadIdx.x;

    __shared__ float xt[16 * 516];
    __shared__ float mu_s[16], rs_s[16];

    // phase 1: unpack o (bf16) into xt
    const int4* og = (const int4*)(o + ((size_t)b * L + l0) * C);
    #pragma unroll
    for (int jj = 0; jj < 4; jj++) {
        int i = tid + jj * 256;                  // < 1024
        int l = i >> 6, c8 = i & 63;
        int4 v = og[l * 64 + c8];
        float4 f0, f1;
        f0.x = bf_lo(v.x); f0.y = bf_hi(v.x); f0.z = bf_lo(v.y); f0.w = bf_hi(v.y);
        f1.x = bf_lo(v.z); f1.y = bf_hi(v.z); f1.z = bf_lo(v.w); f1.w = bf_hi(v.w);
        *(float4*)&xt[l * 516 + c8 * 8]     = f0;
        *(float4*)&xt[l * 516 + c8 * 8 + 4] = f1;
    }
    __syncthreads();

    // phase 2: residual add from q [C, L] (float4 along l)
    const float* qb = q + (size_t)b * C * L + l0;
    #pragma unroll
    for (int jj = 0; jj < 8; jj++) {
        int i = tid + jj * 256;                  // < 2048
        int c = i >> 2, seg = i & 3;
        float4 v = *(const float4*)(qb + (size_t)c * L + seg * 4);
        xt[(seg * 4 + 0) * 516 + c] += v.x;
        xt[(seg * 4 + 1) * 516 + c] += v.y;
        xt[(seg * 4 + 2) * 516 + c] += v.z;
        xt[(seg * 4 + 3) * 516 + c] += v.w;
    }
    __syncthreads();

    // phase 3: mean/var per l-row
    {
        int l = tid >> 4, sub = tid & 15;
        float s = 0.f, ss = 0.f;
        for (int j = 0; j < 32; j++) {
            float v = xt[l * 516 + sub + 16 * j];
            s += v; ss += v * v;
        }
        #pragma unroll
        for (int off = 1; off < 16; off <<= 1) {
            s  += __shfl_xor(s, off, 64);
            ss += __shfl_xor(ss, off, 64);
        }
        if (sub == 0) {
            float mean = s * (1.f / 512.f);
            float var  = ss * (1.f / 512.f) - mean * mean;
            mu_s[l] = mean;
            rs_s[l] = rsqrtf(var + 1e-5f);
        }
    }
    __syncthreads();

    // phase 4: normalize + affine, float4 stores along l
    float* yb = y + (size_t)b * C * L + l0;
    #pragma unroll
    for (int jj = 0; jj < 8; jj++) {
        int i = tid + jj * 256;                  // < 2048
        int c = i >> 2, seg = i & 3;
        float g = gamma[c], be = beta[c];
        float4 r;
        r.x = (xt[(seg * 4 + 0) * 516 + c] - mu_s[seg * 4 + 0]) * rs_s[seg * 4 + 0] * g + be;
        r.y = (xt[(seg * 4 + 1) * 516 + c] - mu_s[seg * 4 + 1]) * rs_s[seg * 4 + 1] * g + be;
        r.z = (xt[(seg * 4 + 2) * 516 + c] - mu_s[seg * 4 + 2]) * rs_s[seg * 4 + 2] * g + be;
        r.w = (xt[(seg * 4 + 3) * 516 + c] - mu_s[seg * 4 + 3]) * rs_s[seg * 4 + 3] * g + be;
        *(float4*)(yb + (size_t)c * L + seg * 4) = r;
    }
}

// ---------------------------------------------------------------------------
extern "C" void kernel_launch(void* const* d_in, const int* in_sizes, int n_in,
                              void* d_out, int out_size, void* d_ws, size_t ws_size,
                              hipStream_t stream)
{
    const float* q     = (const float*)d_in[0];
    const float* k     = (const float*)d_in[1];
    // d_in[2] = mask — analytic
    const float* wq    = (const float*)d_in[3];
    const float* wk    = (const float*)d_in[4];
    const float* wv    = (const float*)d_in[5];
    const float* gamma = (const float*)d_in[6];
    const float* beta  = (const float*)d_in[7];
    float* y = (float*)d_out;

    const size_t N = (size_t)B * H * L * D;      // 4,194,304
    short* qh  = (short*)d_ws;                   // [BH, L, D] bf16
    short* kh  = qh + N;                         // [BH, L, D] bf16
    short* vh  = kh + N;                         // [BH, D, L] bf16
    short* o   = vh + N;                         // [B, L, C] bf16
    short* wtg = o + N;                          // 294912 bf16 A-frag weights

    wprep_kernel<<<1152, 256, 0, stream>>>(wq, wk, wv, wtg);
    conv_kernel<<<2 * B * H * (L / 64), 256, 0, stream>>>(q, k, wtg, qh, kh, vh);
    flash_kernel<<<B * H * (L / 128), 256, 0, stream>>>(qh, kh, vh, o);
    ln_kernel<<<B * (L / 16), 256, 0, stream>>>(o, q, gamma, beta, y);
}